// Round 1
// baseline (1077.369 us; speedup 1.0000x reference)
//
#include <hip/hip_runtime.h>
#include <hip/hip_bf16.h>
#include <cstdint>

// Problem constants
// B=4, D=256, DK=DV=32, NH=8, HS=WS=64, NQ=4096, ratio=2 -> NK=1024

// ---------------- utility ----------------
__global__ void zero32_kernel(float* __restrict__ p){ p[threadIdx.x] = 0.f; }

// wt[(khkw*256+c)*256 + o] = w[o*2304 + c*9 + khkw]
__global__ void convw_t_kernel(const float* __restrict__ w, float* __restrict__ wt){
    int k = blockIdx.x;     // 0..2303  (khkw*256 + c)
    int o = threadIdx.x;    // 0..255
    int c = k & 255, khkw = k >> 8;
    wt[(size_t)k*256 + o] = w[(size_t)o*2304 + c*9 + khkw];
}

// ---------------- generic tiled GEMM + bias: C[M,N] = A[M,K]@B[K,N] + bias ----------------
__launch_bounds__(256)
__global__ void gemm_bias_kernel(const float* __restrict__ A, const float* __restrict__ Bm,
                                 const float* __restrict__ bias, float* __restrict__ C,
                                 int M, int N, int K){
    __shared__ float As[16][68];
    __shared__ float Bs[16][68];
    int t = threadIdx.x;
    int tr = t >> 4, tc = t & 15;
    int m0 = blockIdx.x * 64, n0 = blockIdx.y * 64;
    float acc[4][4] = {};
    for (int k0 = 0; k0 < K; k0 += 16){
        #pragma unroll
        for (int i = 0; i < 4; ++i){
            int e = t + i*256, r = e >> 4, c = e & 15;
            As[c][r] = A[(size_t)(m0+r)*K + k0 + c];
        }
        #pragma unroll
        for (int i = 0; i < 4; ++i){
            int e = t + i*256, r = e >> 6, c = e & 63;
            Bs[r][c] = Bm[(size_t)(k0+r)*N + n0 + c];
        }
        __syncthreads();
        #pragma unroll
        for (int kk = 0; kk < 16; ++kk){
            float a[4], b[4];
            #pragma unroll
            for (int i=0;i<4;++i) a[i] = As[kk][tr*4+i];
            #pragma unroll
            for (int j=0;j<4;++j) b[j] = Bs[kk][tc*4+j];
            #pragma unroll
            for (int i=0;i<4;++i)
                #pragma unroll
                for (int j=0;j<4;++j)
                    acc[i][j] += a[i]*b[j];
        }
        __syncthreads();
    }
    #pragma unroll
    for (int i=0;i<4;++i){
        int m = m0 + tr*4 + i;
        #pragma unroll
        for (int j=0;j<4;++j){
            int n = n0 + tc*4 + j;
            C[(size_t)m*N + n] = acc[i][j] + bias[n];
        }
    }
}

// ---------------- conv as GEMM: Xc[b*1024+pos, o] = im2col(Q) @ Wt + srb ----------------
// M = 4096 rows (b,oh,ow), N = 256, K = 2304 with kidx = (kh*3+kw)*256 + c
__launch_bounds__(256)
__global__ void conv_gemm_kernel(const float* __restrict__ Q, const float* __restrict__ Wt,
                                 const float* __restrict__ srb, float* __restrict__ Xc){
    __shared__ float As[16][68];
    __shared__ float Bs[16][68];
    int t = threadIdx.x;
    int tr = t >> 4, tc = t & 15;
    int m0 = blockIdx.x * 64, n0 = blockIdx.y * 64;
    float acc[4][4] = {};
    for (int k0 = 0; k0 < 2304; k0 += 16){
        #pragma unroll
        for (int i = 0; i < 4; ++i){
            int e = t + i*256, r = e >> 4, c = e & 15;
            int m = m0 + r;
            int bb2 = m >> 10, pos = m & 1023;
            int oh = pos >> 5, ow = pos & 31;
            int kk = k0 + c;
            int khkw = kk >> 8, ch = kk & 255;
            int kh = khkw / 3, kw = khkw - kh*3;
            int ih = oh*2 - 1 + kh, iw = ow*2 - 1 + kw;
            float v = 0.f;
            if ((unsigned)ih < 64u && (unsigned)iw < 64u)
                v = Q[((size_t)bb2*4096 + ih*64 + iw)*256 + ch];
            As[c][r] = v;
        }
        #pragma unroll
        for (int i = 0; i < 4; ++i){
            int e = t + i*256, r = e >> 6, c = e & 63;
            Bs[r][c] = Wt[(size_t)(k0+r)*256 + n0 + c];
        }
        __syncthreads();
        #pragma unroll
        for (int kk = 0; kk < 16; ++kk){
            float a[4], b[4];
            #pragma unroll
            for (int i=0;i<4;++i) a[i] = As[kk][tr*4+i];
            #pragma unroll
            for (int j=0;j<4;++j) b[j] = Bs[kk][tc*4+j];
            #pragma unroll
            for (int i=0;i<4;++i)
                #pragma unroll
                for (int j=0;j<4;++j)
                    acc[i][j] += a[i]*b[j];
        }
        __syncthreads();
    }
    #pragma unroll
    for (int i=0;i<4;++i){
        int m = m0 + tr*4 + i;
        #pragma unroll
        for (int j=0;j<4;++j){
            int n = n0 + tc*4 + j;
            Xc[(size_t)m*256 + n] = acc[i][j] + srb[n];
        }
    }
}

// ---------------- LayerNorm over D=256, in-place, one block per row ----------------
__launch_bounds__(256)
__global__ void ln_kernel(float* __restrict__ X, const float* __restrict__ g, const float* __restrict__ b){
    __shared__ float red[256];
    int row = blockIdx.x, t = threadIdx.x;
    float v = X[(size_t)row*256 + t];
    red[t] = v; __syncthreads();
    #pragma unroll
    for (int s=128; s>0; s>>=1){
        if (t < s) red[t] += red[t+s];
        __syncthreads();
    }
    float mu = red[0] * (1.f/256.f);
    __syncthreads();
    float dv = v - mu;
    red[t] = dv*dv; __syncthreads();
    #pragma unroll
    for (int s=128; s>0; s>>=1){
        if (t < s) red[t] += red[t+s];
        __syncthreads();
    }
    float var = red[0] * (1.f/256.f);
    X[(size_t)row*256 + t] = dv * rsqrtf(var + 1e-5f) * g[t] + b[t];
}

// ---------------- column sums of V per batch: csum[b*256+d] = sum_k v[b,k,d] ----------------
__launch_bounds__(256)
__global__ void colsumv_kernel(const float* __restrict__ Vb, float* __restrict__ csum){
    int bb = blockIdx.x, t = threadIdx.x;
    float s = 0.f;
    for (int k = 0; k < 1024; ++k) s += Vb[((size_t)bb*1024 + k)*256 + t];
    csum[bb*256 + t] = s;
}

// ---------------- fused attention ----------------
// grid: 4*64 blocks (b, q-tile of 64). block: 512 threads (8 waves; wave h = head h, lane = q row).
// per k-chunk of 16: stage K/V to LDS; stage A computes S[i][q][k] for all heads into LDS;
// stage B mixes heads (tfw), online softmax with sum/sumsq tracking, accumulates PV.
#define QT 64
#define KT 16
__launch_bounds__(512)
__global__ void attn_kernel(const float* __restrict__ Qp, const float* __restrict__ Kp,
                            const float* __restrict__ Vp, const float* __restrict__ tfw,
                            const float* __restrict__ tfb, float* __restrict__ outu,
                            float* __restrict__ ssq){
    __shared__ float qL[QT][260];
    __shared__ float kL[KT][260];
    __shared__ float vL[KT][260];
    __shared__ float SL[8][QT][KT+1];
    __shared__ float tfwL[64];

    int t = threadIdx.x;
    int bb = blockIdx.x >> 6;
    int q0 = (blockIdx.x & 63) * QT;

    if (t < 64) tfwL[t] = tfw[t];
    #pragma unroll
    for (int i = 0; i < 32; ++i){
        int e = t + i*512;
        int r = e >> 8, c = e & 255;
        qL[r][c] = Qp[((size_t)(bb*4096 + q0 + r))*256 + c];
    }

    int h  = t >> 6, qq = t & 63;   // stage B: wave h, lane = q row
    int qa = t >> 3, kg = t & 7;    // stage A mapping

    float tb = tfb[h];
    float m = -1e30f, s = 0.f, s2 = 0.f;
    float acc[32];
    #pragma unroll
    for (int d = 0; d < 32; ++d) acc[d] = 0.f;

    __syncthreads();
    float tw[8];
    #pragma unroll
    for (int i = 0; i < 8; ++i) tw[i] = tfwL[h*8 + i];

    for (int kc = 0; kc < 1024; kc += KT){
        // stage K/V chunk
        #pragma unroll
        for (int i = 0; i < 8; ++i){
            int e = t + i*512;
            int r = e >> 8, c = e & 255;
            size_t g = ((size_t)(bb*1024 + kc + r))*256 + c;
            kL[r][c] = Kp[g];
            vL[r][c] = Vp[g];
        }
        __syncthreads();
        // stage A: S[i][qa][k] = (q . k) / sqrt(32)
        #pragma unroll
        for (int i = 0; i < 8; ++i){
            float qf[32];
            #pragma unroll
            for (int d = 0; d < 32; ++d) qf[d] = qL[qa][i*32 + d];
            #pragma unroll
            for (int j = 0; j < 2; ++j){
                int k = kg + j*8;
                float dot = 0.f;
                #pragma unroll
                for (int d = 0; d < 32; ++d) dot += qf[d]*kL[k][i*32 + d];
                SL[i][qa][k] = dot * 0.17677669529663687f;
            }
        }
        __syncthreads();
        // stage B: mix + online softmax + PV
        #pragma unroll 1
        for (int k = 0; k < KT; ++k){
            float L = tb;
            #pragma unroll
            for (int i = 0; i < 8; ++i) L += tw[i]*SL[i][qq][k];
            const float* vp = &vL[k][h*32];
            if (L <= m){
                float e = __expf(L - m);
                s += e; s2 += e*e;
                #pragma unroll
                for (int d = 0; d < 32; ++d) acc[d] += e*vp[d];
            } else {
                float c = __expf(m - L);
                m = L;
                s = s*c + 1.f; s2 = s2*c*c + 1.f;
                #pragma unroll
                for (int d = 0; d < 32; ++d) acc[d] = acc[d]*c + vp[d];
            }
        }
        __syncthreads();
    }

    float inv = 1.f / s;
    float* op = &outu[((size_t)(bb*4096 + q0 + qq))*256 + h*32];
    #pragma unroll
    for (int d = 0; d < 32; ++d) op[d] = acc[d]*inv;

    float rowssq = s2*inv*inv;
    float* red = &SL[0][0][0];
    red[t] = rowssq;
    __syncthreads();
    if (t < 8){
        float tot = 0.f;
        for (int i = 0; i < 64; ++i) tot += red[t*64 + i];
        atomicAdd(&ssq[bb*8 + t], tot);
    }
}

// ---------------- rs[b,h] = rsqrt(ssq/(NQ*NK) - mu^2 + eps) ----------------
__global__ void rs_kernel(const float* __restrict__ ssq, float* __restrict__ rs){
    int t = threadIdx.x;  // 32
    const float mu = 1.f/1024.f;
    float var = ssq[t] * (1.f/(4096.f*1024.f)) - mu*mu;
    rs[t] = rsqrtf(var + 1e-5f);
}

// ---------------- corr[b][n] = sum_d rs[b,d>>5]*mu*csum[b,d]*Wo[d][n] ----------------
__launch_bounds__(256)
__global__ void corr_kernel(const float* __restrict__ rs, const float* __restrict__ csum,
                            const float* __restrict__ Wo, float* __restrict__ corr){
    int bb = blockIdx.x, n = threadIdx.x;
    const float mu = 1.f/1024.f;
    float acc = 0.f;
    for (int d = 0; d < 256; ++d){
        float sc = rs[bb*8 + (d>>5)] * mu * csum[bb*256 + d];
        acc += sc * Wo[(size_t)d*256 + n];
    }
    corr[bb*256 + n] = acc;
}

// ---------------- final: C[m][n] = sum_d (rs*outu)[m][d]*Wo[d][n] + bo[n] - corr[b][n] ----------------
__launch_bounds__(256)
__global__ void final_gemm_kernel(const float* __restrict__ A, const float* __restrict__ Bm,
                                  const float* __restrict__ rsb, const float* __restrict__ bo,
                                  const float* __restrict__ corr, float* __restrict__ C){
    __shared__ float As[16][68];
    __shared__ float Bs[16][68];
    __shared__ float rsL[8];
    int t = threadIdx.x;
    int tr = t >> 4, tc = t & 15;
    int m0 = blockIdx.x * 64, n0 = blockIdx.y * 64;
    int bb = m0 >> 12;
    if (t < 8) rsL[t] = rsb[bb*8 + t];
    __syncthreads();
    float acc[4][4] = {};
    for (int k0 = 0; k0 < 256; k0 += 16){
        #pragma unroll
        for (int i = 0; i < 4; ++i){
            int e = t + i*256, r = e >> 4, c = e & 15;
            As[c][r] = A[(size_t)(m0+r)*256 + k0 + c] * rsL[(k0+c)>>5];
        }
        #pragma unroll
        for (int i = 0; i < 4; ++i){
            int e = t + i*256, r = e >> 6, c = e & 63;
            Bs[r][c] = Bm[(size_t)(k0+r)*256 + n0 + c];
        }
        __syncthreads();
        #pragma unroll
        for (int kk = 0; kk < 16; ++kk){
            float a[4], b[4];
            #pragma unroll
            for (int i=0;i<4;++i) a[i] = As[kk][tr*4+i];
            #pragma unroll
            for (int j=0;j<4;++j) b[j] = Bs[kk][tc*4+j];
            #pragma unroll
            for (int i=0;i<4;++i)
                #pragma unroll
                for (int j=0;j<4;++j)
                    acc[i][j] += a[i]*b[j];
        }
        __syncthreads();
    }
    #pragma unroll
    for (int i=0;i<4;++i){
        int m = m0 + tr*4 + i;
        #pragma unroll
        for (int j=0;j<4;++j){
            int n = n0 + tc*4 + j;
            C[(size_t)m*256 + n] = acc[i][j] + bo[n] - corr[bb*256 + n];
        }
    }
}

extern "C" void kernel_launch(void* const* d_in, const int* in_sizes, int n_in,
                              void* d_out, int out_size, void* d_ws, size_t ws_size,
                              hipStream_t stream) {
    const float* query = (const float*)d_in[0];
    // d_in[1] (key), d_in[2] (value) are unused by the reference
    const float* Wq  = (const float*)d_in[3];
    const float* bq  = (const float*)d_in[4];
    const float* Wk  = (const float*)d_in[5];
    const float* bk  = (const float*)d_in[6];
    const float* Wv  = (const float*)d_in[7];
    const float* bv  = (const float*)d_in[8];
    const float* Wo  = (const float*)d_in[9];
    const float* bo  = (const float*)d_in[10];
    const float* srw = (const float*)d_in[11];
    const float* srb = (const float*)d_in[12];
    const float* lng = (const float*)d_in[13];
    const float* lnb = (const float*)d_in[14];
    const float* tfw = (const float*)d_in[15];
    const float* tfb = (const float*)d_in[16];
    float* out = (float*)d_out;

    float* ws = (float*)d_ws;
    float* qbuf = ws;                  // 16384*256 = 4,194,304
    float* outu = ws + 4194304;        // 4,194,304
    float* xred = ws + 8388608;        // 4096*256 = 1,048,576
    float* kbuf = ws + 9437184;        // 1,048,576
    float* vbuf = ws + 10485760;       // 1,048,576
    float* wt   = ws + 11534336;       // 2304*256 = 589,824
    float* csum = ws + 12124160;       // 1024
    float* ssq  = ws + 12125184;       // 32
    float* rsb  = ws + 12125216;       // 32
    float* corr = ws + 12125248;       // 1024

    zero32_kernel<<<1, 32, 0, stream>>>(ssq);
    convw_t_kernel<<<2304, 256, 0, stream>>>(srw, wt);
    // q projection: (16384,256) @ (256,256) + bq
    gemm_bias_kernel<<<dim3(256, 4), 256, 0, stream>>>(query, Wq, bq, qbuf, 16384, 256, 256);
    // spatial-reduction conv as GEMM, then LayerNorm in place
    conv_gemm_kernel<<<dim3(64, 4), 256, 0, stream>>>(query, wt, srb, xred);
    ln_kernel<<<4096, 256, 0, stream>>>(xred, lng, lnb);
    // k, v projections
    gemm_bias_kernel<<<dim3(64, 4), 256, 0, stream>>>(xred, Wk, bk, kbuf, 4096, 256, 256);
    gemm_bias_kernel<<<dim3(64, 4), 256, 0, stream>>>(xred, Wv, bv, vbuf, 4096, 256, 256);
    colsumv_kernel<<<4, 256, 0, stream>>>(vbuf, csum);
    // fused attention (scores + head-mix + softmax + sumsq + PV)
    attn_kernel<<<256, 512, 0, stream>>>(qbuf, kbuf, vbuf, tfw, tfb, outu, ssq);
    rs_kernel<<<1, 32, 0, stream>>>(ssq, rsb);
    corr_kernel<<<4, 256, 0, stream>>>(rsb, csum, Wo, corr);
    // output projection with folded instance-norm affine
    final_gemm_kernel<<<dim3(256, 4), 256, 0, stream>>>(outu, Wo, rsb, bo, corr, out);
}

// Round 2
// 579.559 us; speedup vs baseline: 1.8589x; 1.8589x over previous
//
#include <hip/hip_runtime.h>
#include <hip/hip_bf16.h>
#include <cstdint>

// Problem constants: B=4, D=256, DK=DV=32, NH=8, HS=WS=64, NQ=4096, NK=1024

typedef _Float16 f16;
typedef f16 f16x4 __attribute__((ext_vector_type(4)));
typedef f16 f16x8 __attribute__((ext_vector_type(8)));
typedef float f32x4 __attribute__((ext_vector_type(4)));

// ---------------- utility ----------------
__global__ void zero32_kernel(float* __restrict__ p){ p[threadIdx.x] = 0.f; }

// wt[(khkw*256+c)*256 + o] = w[o*2304 + c*9 + khkw]
__global__ void convw_t_kernel(const float* __restrict__ w, float* __restrict__ wt){
    int k = blockIdx.x;     // 0..2303  (khkw*256 + c)
    int o = threadIdx.x;    // 0..255
    int c = k & 255, khkw = k >> 8;
    wt[(size_t)k*256 + o] = w[(size_t)o*2304 + c*9 + khkw];
}

// ---------------- generic tiled GEMM + bias: C[M,N] = A[M,K]@B[K,N] + bias ----------------
__launch_bounds__(256)
__global__ void gemm_bias_kernel(const float* __restrict__ A, const float* __restrict__ Bm,
                                 const float* __restrict__ bias, float* __restrict__ C,
                                 int M, int N, int K){
    __shared__ float As[16][68];
    __shared__ float Bs[16][68];
    int t = threadIdx.x;
    int tr = t >> 4, tc = t & 15;
    int m0 = blockIdx.x * 64, n0 = blockIdx.y * 64;
    float acc[4][4] = {};
    for (int k0 = 0; k0 < K; k0 += 16){
        #pragma unroll
        for (int i = 0; i < 4; ++i){
            int e = t + i*256, r = e >> 4, c = e & 15;
            As[c][r] = A[(size_t)(m0+r)*K + k0 + c];
        }
        #pragma unroll
        for (int i = 0; i < 4; ++i){
            int e = t + i*256, r = e >> 6, c = e & 63;
            Bs[r][c] = Bm[(size_t)(k0+r)*N + n0 + c];
        }
        __syncthreads();
        #pragma unroll
        for (int kk = 0; kk < 16; ++kk){
            float a[4], b[4];
            #pragma unroll
            for (int i=0;i<4;++i) a[i] = As[kk][tr*4+i];
            #pragma unroll
            for (int j=0;j<4;++j) b[j] = Bs[kk][tc*4+j];
            #pragma unroll
            for (int i=0;i<4;++i)
                #pragma unroll
                for (int j=0;j<4;++j)
                    acc[i][j] += a[i]*b[j];
        }
        __syncthreads();
    }
    #pragma unroll
    for (int i=0;i<4;++i){
        int m = m0 + tr*4 + i;
        #pragma unroll
        for (int j=0;j<4;++j){
            int n = n0 + tc*4 + j;
            C[(size_t)m*N + n] = acc[i][j] + bias[n];
        }
    }
}

// ---------------- conv as GEMM: Xc[b*1024+pos, o] = im2col(Q) @ Wt + srb ----------------
__launch_bounds__(256)
__global__ void conv_gemm_kernel(const float* __restrict__ Q, const float* __restrict__ Wt,
                                 const float* __restrict__ srb, float* __restrict__ Xc){
    __shared__ float As[16][68];
    __shared__ float Bs[16][68];
    int t = threadIdx.x;
    int tr = t >> 4, tc = t & 15;
    int m0 = blockIdx.x * 64, n0 = blockIdx.y * 64;
    float acc[4][4] = {};
    for (int k0 = 0; k0 < 2304; k0 += 16){
        #pragma unroll
        for (int i = 0; i < 4; ++i){
            int e = t + i*256, r = e >> 4, c = e & 15;
            int m = m0 + r;
            int bb2 = m >> 10, pos = m & 1023;
            int oh = pos >> 5, ow = pos & 31;
            int kk = k0 + c;
            int khkw = kk >> 8, ch = kk & 255;
            int kh = khkw / 3, kw = khkw - kh*3;
            int ih = oh*2 - 1 + kh, iw = ow*2 - 1 + kw;
            float v = 0.f;
            if ((unsigned)ih < 64u && (unsigned)iw < 64u)
                v = Q[((size_t)bb2*4096 + ih*64 + iw)*256 + ch];
            As[c][r] = v;
        }
        #pragma unroll
        for (int i = 0; i < 4; ++i){
            int e = t + i*256, r = e >> 6, c = e & 63;
            Bs[r][c] = Wt[(size_t)(k0+r)*256 + n0 + c];
        }
        __syncthreads();
        #pragma unroll
        for (int kk = 0; kk < 16; ++kk){
            float a[4], b[4];
            #pragma unroll
            for (int i=0;i<4;++i) a[i] = As[kk][tr*4+i];
            #pragma unroll
            for (int j=0;j<4;++j) b[j] = Bs[kk][tc*4+j];
            #pragma unroll
            for (int i=0;i<4;++i)
                #pragma unroll
                for (int j=0;j<4;++j)
                    acc[i][j] += a[i]*b[j];
        }
        __syncthreads();
    }
    #pragma unroll
    for (int i=0;i<4;++i){
        int m = m0 + tr*4 + i;
        #pragma unroll
        for (int j=0;j<4;++j){
            int n = n0 + tc*4 + j;
            Xc[(size_t)m*256 + n] = acc[i][j] + srb[n];
        }
    }
}

// ---------------- LayerNorm over D=256, in-place, one block per row ----------------
__launch_bounds__(256)
__global__ void ln_kernel(float* __restrict__ X, const float* __restrict__ g, const float* __restrict__ b){
    __shared__ float red[256];
    int row = blockIdx.x, t = threadIdx.x;
    float v = X[(size_t)row*256 + t];
    red[t] = v; __syncthreads();
    #pragma unroll
    for (int s=128; s>0; s>>=1){
        if (t < s) red[t] += red[t+s];
        __syncthreads();
    }
    float mu = red[0] * (1.f/256.f);
    __syncthreads();
    float dv = v - mu;
    red[t] = dv*dv; __syncthreads();
    #pragma unroll
    for (int s=128; s>0; s>>=1){
        if (t < s) red[t] += red[t+s];
        __syncthreads();
    }
    float var = red[0] * (1.f/256.f);
    X[(size_t)row*256 + t] = dv * rsqrtf(var + 1e-5f) * g[t] + b[t];
}

// ---------------- V transpose + fp16: VT[b][d][k] = (f16)V[b][k][d] ----------------
__launch_bounds__(256)
__global__ void vtran_kernel(const float* __restrict__ V, f16* __restrict__ VT){
    __shared__ float LT[32][33];
    int b = blockIdx.z, k0 = blockIdx.x*32, d0 = blockIdx.y*32;
    int t = threadIdx.x;
    int k = t >> 3, c0 = (t & 7)*4;
    float4 v = *(const float4*)&V[((size_t)(b*1024 + k0 + k))*256 + d0 + c0];
    LT[k][c0] = v.x; LT[k][c0+1] = v.y; LT[k][c0+2] = v.z; LT[k][c0+3] = v.w;
    __syncthreads();
    int d = t >> 3, kc0 = (t & 7)*4;
    f16x4 h = { (f16)LT[kc0][d], (f16)LT[kc0+1][d], (f16)LT[kc0+2][d], (f16)LT[kc0+3][d] };
    *(f16x4*)&VT[((size_t)(b*256 + d0 + d))*1024 + k0 + kc0] = h;
}

// ---------------- K fp16 convert (row-major unchanged) ----------------
__launch_bounds__(256)
__global__ void kcvt_kernel(const float* __restrict__ in, f16* __restrict__ out){
    size_t idx = ((size_t)blockIdx.x*256 + threadIdx.x) * 8;
    float4 a = *(const float4*)&in[idx];
    float4 b = *(const float4*)&in[idx+4];
    f16x8 h = { (f16)a.x,(f16)a.y,(f16)a.z,(f16)a.w,(f16)b.x,(f16)b.y,(f16)b.z,(f16)b.w };
    *(f16x8*)&out[idx] = h;
}

// ---------------- csum[b*256+d] = sum_k VT[b][d][k] (fp16 source, consistent w/ PV) ----------------
__launch_bounds__(256)
__global__ void colsum2_kernel(const f16* __restrict__ VT, float* __restrict__ csum){
    __shared__ float red[256];
    int bd = blockIdx.x, t = threadIdx.x;
    f16x4 h = *(const f16x4*)&VT[(size_t)bd*1024 + t*4];
    red[t] = (float)h[0] + (float)h[1] + (float)h[2] + (float)h[3];
    __syncthreads();
    #pragma unroll
    for (int s = 128; s > 0; s >>= 1){
        if (t < s) red[t] += red[t+s];
        __syncthreads();
    }
    if (t == 0) csum[bd] = red[0];
}

// ---------------- fused MFMA attention ----------------
// Mix folded into Q: L_o[q,k] = sum_c (tfw[o,c>>5]/sqrt(32) * Q[q,c]) * K[k,c] + tfb[o].
// Swapped QK^T: S^T = K~ . Q~^T via mfma 16x16x32 f16 (C: row=k=(l>>4)*4+j, col=q=l&15).
// p~ = exp(L)-1 packs directly into B-frag of mfma 16x16x16 f16; A = V^T from LDS.
// Epilogue: outu = [(p-1)@v]/s + colsum*(1/s - 1/1024); InstanceNorm rs applied in final GEMM.
__launch_bounds__(512, 2)
__global__ void attn2_kernel(const float* __restrict__ Qp, const f16* __restrict__ Kh,
                             const f16* __restrict__ VTh, const float* __restrict__ tfw,
                             const float* __restrict__ tfb, const float* __restrict__ csum,
                             float* __restrict__ outu, float* __restrict__ ssq){
    __shared__ f16 QL[32][264];
    __shared__ f16 KL[32][264];
    __shared__ f16 VTL[256][40];

    const int t  = threadIdx.x;
    const int bb = blockIdx.x >> 7;          // 128 q-tiles of 32 per batch
    const int q0 = (blockIdx.x & 127) * 32;
    const int o  = t >> 6;                   // wave = output head
    const int l  = t & 63;
    const int g  = l >> 4;
    const int r  = l & 15;

    // stage Q tile (f32 -> f16), 32x256
    #pragma unroll
    for (int it = 0; it < 4; ++it){
        int e4 = t + it*512;
        int row = e4 >> 6;
        int c0  = (e4 & 63) * 4;
        float4 v = *(const float4*)&Qp[((size_t)(bb*4096 + q0 + row))*256 + c0];
        f16x4 h = { (f16)v.x, (f16)v.y, (f16)v.z, (f16)v.w };
        *(f16x4*)&QL[row][c0] = h;
    }
    __syncthreads();

    const float tb = tfb[o];
    // Q~ B-fragments, scale tfw[o,i]/sqrt(32) folded per 32-block
    f16x8 qf[2][8];
    #pragma unroll
    for (int i = 0; i < 8; ++i){
        f16 sc = (f16)(tfw[o*8 + i] * 0.17677669529663687f);
        f16x8 scv = { sc,sc,sc,sc,sc,sc,sc,sc };
        #pragma unroll
        for (int qs = 0; qs < 2; ++qs){
            f16x8 v = *(const f16x8*)&QL[qs*16 + r][i*32 + g*8];
            qf[qs][i] = v * scv;
        }
    }

    f32x4 oacc[2][2] = { { {0,0,0,0},{0,0,0,0} }, { {0,0,0,0},{0,0,0,0} } };
    float s_part[2]  = {0.f, 0.f};
    float q2_part[2] = {0.f, 0.f};

    const f16* Khb = Kh  + (size_t)bb*1024*256;
    const f16* Vtb = VTh + (size_t)bb*256*1024;

    for (int kc = 0; kc < 1024; kc += 32){
        // stage K (32x256) and V^T (256x32) fp16 tiles
        #pragma unroll
        for (int it = 0; it < 2; ++it){
            int e = t + it*512;
            int row = e >> 5, c = (e & 31)*8;
            *(f16x8*)&KL[row][c] = *(const f16x8*)&Khb[(size_t)(kc + row)*256 + c];
            int d = e >> 2, qt = (e & 3)*8;
            *(f16x8*)&VTL[d][qt] = *(const f16x8*)&Vtb[(size_t)d*1024 + kc + qt];
        }
        __syncthreads();
        #pragma unroll
        for (int ks = 0; ks < 2; ++ks){
            f16x8 kf[8];
            #pragma unroll
            for (int i = 0; i < 8; ++i)
                kf[i] = *(const f16x8*)&KL[ks*16 + r][i*32 + g*8];
            f16x4 va[2];
            #pragma unroll
            for (int dh = 0; dh < 2; ++dh)
                va[dh] = *(const f16x4*)&VTL[o*32 + dh*16 + r][ks*16 + g*4];
            #pragma unroll
            for (int qs = 0; qs < 2; ++qs){
                f32x4 acc = {0,0,0,0};
                #pragma unroll
                for (int i = 0; i < 8; ++i)
                    acc = __builtin_amdgcn_mfma_f32_16x16x32_f16(kf[i], qf[qs][i], acc, 0, 0, 0);
                f16x4 pb;
                float ps = 0.f, ps2 = 0.f;
                #pragma unroll
                for (int j = 0; j < 4; ++j){
                    float p = __expf(acc[j] + tb);
                    ps += p; ps2 += p*p;
                    pb[j] = (f16)(p - 1.0f);
                }
                s_part[qs]  += ps;
                q2_part[qs] += ps2;
                #pragma unroll
                for (int dh = 0; dh < 2; ++dh)
                    oacc[qs][dh] = __builtin_amdgcn_mfma_f32_16x16x16f16(va[dh], pb, oacc[qs][dh], 0, 0, 0);
            }
        }
        __syncthreads();
    }

    // epilogue: per-q row sums live across lane groups g (lanes r, r+16, r+32, r+48)
    float s2tot = 0.f;
    #pragma unroll
    for (int qs = 0; qs < 2; ++qs){
        float s = s_part[qs];
        s += __shfl_xor(s, 16);
        s += __shfl_xor(s, 32);
        float inv = 1.0f / s;
        float corrf = (1.0f - s * (1.0f/1024.0f)) * inv;
        float q2 = q2_part[qs];
        q2 += __shfl_xor(q2, 16);
        q2 += __shfl_xor(q2, 32);
        s2tot += q2 * inv * inv;
        int q = q0 + qs*16 + r;
        #pragma unroll
        for (int dh = 0; dh < 2; ++dh){
            int d = o*32 + dh*16 + g*4;
            float4 cs = *(const float4*)&csum[bb*256 + d];
            float4 ov;
            ov.x = oacc[qs][dh][0]*inv + cs.x*corrf;
            ov.y = oacc[qs][dh][1]*inv + cs.y*corrf;
            ov.z = oacc[qs][dh][2]*inv + cs.z*corrf;
            ov.w = oacc[qs][dh][3]*inv + cs.w*corrf;
            *(float4*)&outu[((size_t)(bb*4096 + q))*256 + d] = ov;
        }
    }
    s2tot *= 0.25f;  // each q replicated across 4 g-groups
    #pragma unroll
    for (int off = 1; off < 64; off <<= 1)
        s2tot += __shfl_xor(s2tot, off);
    if (l == 0) atomicAdd(&ssq[bb*8 + o], s2tot);
}

// ---------------- rs[b,h] = rsqrt(ssq/(NQ*NK) - mu^2 + eps) ----------------
__global__ void rs_kernel(const float* __restrict__ ssq, float* __restrict__ rs){
    int t = threadIdx.x;  // 32
    const float mu = 1.f/1024.f;
    float var = ssq[t] * (1.f/(4096.f*1024.f)) - mu*mu;
    rs[t] = rsqrtf(var + 1e-5f);
}

// ---------------- final: C[m][n] = sum_d (rs*outu)[m][d]*Wo[d][n] + bo[n] ----------------
__launch_bounds__(256)
__global__ void final_gemm_kernel(const float* __restrict__ A, const float* __restrict__ Bm,
                                  const float* __restrict__ rsb, const float* __restrict__ bo,
                                  float* __restrict__ C){
    __shared__ float As[16][68];
    __shared__ float Bs[16][68];
    __shared__ float rsL[8];
    int t = threadIdx.x;
    int tr = t >> 4, tc = t & 15;
    int m0 = blockIdx.x * 64, n0 = blockIdx.y * 64;
    int bb = m0 >> 12;
    if (t < 8) rsL[t] = rsb[bb*8 + t];
    __syncthreads();
    float acc[4][4] = {};
    for (int k0 = 0; k0 < 256; k0 += 16){
        #pragma unroll
        for (int i = 0; i < 4; ++i){
            int e = t + i*256, r = e >> 4, c = e & 15;
            As[c][r] = A[(size_t)(m0+r)*256 + k0 + c] * rsL[(k0+c)>>5];
        }
        #pragma unroll
        for (int i = 0; i < 4; ++i){
            int e = t + i*256, r = e >> 6, c = e & 63;
            Bs[r][c] = Bm[(size_t)(k0+r)*256 + n0 + c];
        }
        __syncthreads();
        #pragma unroll
        for (int kk = 0; kk < 16; ++kk){
            float a[4], b[4];
            #pragma unroll
            for (int i=0;i<4;++i) a[i] = As[kk][tr*4+i];
            #pragma unroll
            for (int j=0;j<4;++j) b[j] = Bs[kk][tc*4+j];
            #pragma unroll
            for (int i=0;i<4;++i)
                #pragma unroll
                for (int j=0;j<4;++j)
                    acc[i][j] += a[i]*b[j];
        }
        __syncthreads();
    }
    #pragma unroll
    for (int i=0;i<4;++i){
        int m = m0 + tr*4 + i;
        #pragma unroll
        for (int j=0;j<4;++j){
            int n = n0 + tc*4 + j;
            C[(size_t)m*256 + n] = acc[i][j] + bo[n];
        }
    }
}

extern "C" void kernel_launch(void* const* d_in, const int* in_sizes, int n_in,
                              void* d_out, int out_size, void* d_ws, size_t ws_size,
                              hipStream_t stream) {
    const float* query = (const float*)d_in[0];
    const float* Wq  = (const float*)d_in[3];
    const float* bq  = (const float*)d_in[4];
    const float* Wk  = (const float*)d_in[5];
    const float* bk  = (const float*)d_in[6];
    const float* Wv  = (const float*)d_in[7];
    const float* bv  = (const float*)d_in[8];
    const float* Wo  = (const float*)d_in[9];
    const float* bo  = (const float*)d_in[10];
    const float* srw = (const float*)d_in[11];
    const float* srb = (const float*)d_in[12];
    const float* lng = (const float*)d_in[13];
    const float* lnb = (const float*)d_in[14];
    const float* tfw = (const float*)d_in[15];
    const float* tfb = (const float*)d_in[16];
    float* out = (float*)d_out;

    float* ws = (float*)d_ws;
    float* qbuf = ws;                  // 4,194,304 f32
    float* outu = ws + 4194304;        // 4,194,304
    float* xred = ws + 8388608;        // 1,048,576
    float* kbuf = ws + 9437184;        // 1,048,576
    float* vbuf = ws + 10485760;       // 1,048,576 (f32 V; later reused for kh f16)
    float* wt   = ws + 11534336;       // 589,824
    f16*   vth  = (f16*)(ws + 12124160);   // 1,048,576 f16 = 524,288 f32 slots
    float* csum = ws + 12648448;       // 1024
    float* ssq  = ws + 12649472;       // 32
    float* rsb  = ws + 12649504;       // 32
    f16*   kh   = (f16*)vbuf;          // aliases vbuf region (valid after vtran)

    zero32_kernel<<<1, 32, 0, stream>>>(ssq);
    convw_t_kernel<<<2304, 256, 0, stream>>>(srw, wt);
    // q projection: (16384,256) @ (256,256) + bq
    gemm_bias_kernel<<<dim3(256, 4), 256, 0, stream>>>(query, Wq, bq, qbuf, 16384, 256, 256);
    // spatial-reduction conv as GEMM, then LayerNorm in place
    conv_gemm_kernel<<<dim3(64, 4), 256, 0, stream>>>(query, wt, srb, xred);
    ln_kernel<<<4096, 256, 0, stream>>>(xred, lng, lnb);
    // k, v projections (f32)
    gemm_bias_kernel<<<dim3(64, 4), 256, 0, stream>>>(xred, Wk, bk, kbuf, 4096, 256, 256);
    gemm_bias_kernel<<<dim3(64, 4), 256, 0, stream>>>(xred, Wv, bv, vbuf, 4096, 256, 256);
    // fp16 conversions: V transpose first (reads vbuf), then K convert into vbuf region
    vtran_kernel<<<dim3(32, 8, 4), 256, 0, stream>>>(vbuf, vth);
    kcvt_kernel<<<512, 256, 0, stream>>>(kbuf, kh);
    colsum2_kernel<<<1024, 256, 0, stream>>>(vth, csum);
    // fused MFMA attention (scores + folded head-mix + softmax + sumsq + centered PV + colsum corr)
    attn2_kernel<<<512, 512, 0, stream>>>(qbuf, kh, vth, tfw, tfb, csum, outu, ssq);
    rs_kernel<<<1, 32, 0, stream>>>(ssq, rsb);
    // output projection with folded instance-norm scale
    final_gemm_kernel<<<dim3(256, 4), 256, 0, stream>>>(outu, Wo, rsb, bo, out);
}

// Round 4
// 323.874 us; speedup vs baseline: 3.3265x; 1.7895x over previous
//
#include <hip/hip_runtime.h>
#include <hip/hip_bf16.h>
#include <cstdint>

// Problem constants: B=4, D=256, DK=DV=32, NH=8, HS=WS=64, NQ=4096, NK=1024

typedef _Float16 f16;
typedef f16 f16x4 __attribute__((ext_vector_type(4)));
typedef f16 f16x8 __attribute__((ext_vector_type(8)));
typedef float f32x4 __attribute__((ext_vector_type(4)));

// ---------------- utility ----------------
__global__ void zero32_kernel(float* __restrict__ p){ p[threadIdx.x] = 0.f; }

// query f32 -> f16, 8 elems/thread
__launch_bounds__(256)
__global__ void qcvt_kernel(const float* __restrict__ in, f16* __restrict__ out){
    size_t idx = ((size_t)blockIdx.x*256 + threadIdx.x) * 8;
    float4 a = *(const float4*)&in[idx];
    float4 b = *(const float4*)&in[idx+4];
    f16x8 h = { (f16)a.x,(f16)a.y,(f16)a.z,(f16)a.w,(f16)b.x,(f16)b.y,(f16)b.z,(f16)b.w };
    *(f16x8*)&out[idx] = h;
}

// W (256x256 f32, row=in k, col=out n) -> WT (256x256 f16, row=n, col=k)
__launch_bounds__(256)
__global__ void wcvtT_kernel(const float* __restrict__ W, f16* __restrict__ WT){
    __shared__ float L[32][33];
    int r0 = blockIdx.x*32, c0 = blockIdx.y*32;
    int t = threadIdx.x;
    int rr = t >> 3, cc0 = (t & 7)*4;
    float4 v = *(const float4*)&W[(size_t)(r0+rr)*256 + c0 + cc0];
    L[rr][cc0] = v.x; L[rr][cc0+1] = v.y; L[rr][cc0+2] = v.z; L[rr][cc0+3] = v.w;
    __syncthreads();
    int c = t >> 3, rg = (t & 7)*4;
    f16x4 h = { (f16)L[rg][c], (f16)L[rg+1][c], (f16)L[rg+2][c], (f16)L[rg+3][c] };
    *(f16x4*)&WT[(size_t)(c0+c)*256 + r0 + rg] = h;
}

// conv weight OIHW (256,256,3,3) -> wtT[o][khkw*256+c] f16
__launch_bounds__(256)
__global__ void convwT_kernel(const float* __restrict__ w, f16* __restrict__ wtT){
    int o = blockIdx.x, t = threadIdx.x;
    #pragma unroll
    for (int kk = 0; kk < 9; ++kk)
        wtT[(size_t)o*2304 + kk*256 + t] = (f16)w[(size_t)o*2304 + t*9 + kk];
}

// ---------------- MFMA GEMM: C[M,256] = A[M,K](f16) @ BT[256,K](f16)^T + bias ----------------
// 256 threads = 4 waves (2x2). Wave tile (BM/2)x(BN/2). 16x16x32 f16 MFMA.
template<int BM, int BN, bool OUTF16>
__launch_bounds__(256)
__global__ void mfma_gemm(const f16* __restrict__ A, const f16* __restrict__ BT,
                          const float* __restrict__ bias, void* __restrict__ Cout, int K){
    constexpr int MI = BM/32, NI = BN/32;
    __shared__ f16 As[BM][40];
    __shared__ f16 Bs[BN][40];
    int t = threadIdx.x;
    int wid = t >> 6, l = t & 63;
    int wr = wid >> 1, wc = wid & 1;
    int lr = l & 15, lg = l >> 4;
    int m0 = blockIdx.x * BM, n0 = blockIdx.y * BN;

    f32x4 acc[MI][NI] = {};
    for (int k0 = 0; k0 < K; k0 += 32){
        #pragma unroll
        for (int i = 0; i < BM/64; ++i){
            int e = t + i*256, r = e >> 2, c8 = (e & 3)*8;
            *(f16x8*)&As[r][c8] = *(const f16x8*)&A[(size_t)(m0+r)*K + k0 + c8];
        }
        #pragma unroll
        for (int i = 0; i < BN/64; ++i){
            int e = t + i*256, r = e >> 2, c8 = (e & 3)*8;
            *(f16x8*)&Bs[r][c8] = *(const f16x8*)&BT[(size_t)(n0+r)*K + k0 + c8];
        }
        __syncthreads();
        f16x8 af[MI], bf[NI];
        #pragma unroll
        for (int mi = 0; mi < MI; ++mi)
            af[mi] = *(const f16x8*)&As[wr*(BM/2) + mi*16 + lr][lg*8];
        #pragma unroll
        for (int ni = 0; ni < NI; ++ni)
            bf[ni] = *(const f16x8*)&Bs[wc*(BN/2) + ni*16 + lr][lg*8];
        #pragma unroll
        for (int mi = 0; mi < MI; ++mi)
            #pragma unroll
            for (int ni = 0; ni < NI; ++ni)
                acc[mi][ni] = __builtin_amdgcn_mfma_f32_16x16x32_f16(af[mi], bf[ni], acc[mi][ni], 0, 0, 0);
        __syncthreads();
    }
    #pragma unroll
    for (int mi = 0; mi < MI; ++mi){
        #pragma unroll
        for (int ni = 0; ni < NI; ++ni){
            int n = n0 + wc*(BN/2) + ni*16 + lr;
            float bv = bias[n];
            #pragma unroll
            for (int j = 0; j < 4; ++j){
                int m = m0 + wr*(BM/2) + mi*16 + lg*4 + j;
                float v = acc[mi][ni][j] + bv;
                if (OUTF16) ((f16*)Cout)[(size_t)m*256 + n] = (f16)v;
                else        ((float*)Cout)[(size_t)m*256 + n] = v;
            }
        }
    }
}

// ---------------- conv as MFMA GEMM: im2col(qh) @ wtT^T + srb -> f32 ----------------
// M=4096 (b,oh,ow), N=256, K=2304; K-step 32 stays within one khkw block.
__launch_bounds__(256)
__global__ void conv_mfma_kernel(const f16* __restrict__ qh, const f16* __restrict__ wtT,
                                 const float* __restrict__ srb, float* __restrict__ Xc){
    __shared__ f16 As[64][40];
    __shared__ f16 Bs[64][40];
    int t = threadIdx.x;
    int wid = t >> 6, l = t & 63;
    int wr = wid >> 1, wc = wid & 1;
    int lr = l & 15, lg = l >> 4;
    int m0 = blockIdx.x * 64, n0 = blockIdx.y * 64;

    // per-thread A staging geometry (one f16x8 per K-step)
    int r = t >> 2, c8 = (t & 3)*8;
    int m = m0 + r;
    int bb = m >> 10, pos = m & 1023;
    int oh = pos >> 5, ow = pos & 31;
    const f16* qb = qh + (size_t)bb*4096*256;

    f32x4 acc[2][2] = {};
    for (int k0 = 0; k0 < 2304; k0 += 32){
        int khkw = k0 >> 8;
        int kh = (khkw < 3) ? 0 : ((khkw < 6) ? 1 : 2);
        int kw = khkw - kh*3;
        int ih = oh*2 - 1 + kh, iw = ow*2 - 1 + kw;
        int kc = (k0 & 255) + c8;
        f16x8 av = {};
        if ((unsigned)ih < 64u && (unsigned)iw < 64u)
            av = *(const f16x8*)&qb[((size_t)(ih*64 + iw))*256 + kc];
        *(f16x8*)&As[r][c8] = av;
        *(f16x8*)&Bs[r][c8] = *(const f16x8*)&wtT[(size_t)(n0+r)*2304 + k0 + c8];
        __syncthreads();
        f16x8 af[2], bf[2];
        #pragma unroll
        for (int mi = 0; mi < 2; ++mi)
            af[mi] = *(const f16x8*)&As[wr*32 + mi*16 + lr][lg*8];
        #pragma unroll
        for (int ni = 0; ni < 2; ++ni)
            bf[ni] = *(const f16x8*)&Bs[wc*32 + ni*16 + lr][lg*8];
        #pragma unroll
        for (int mi = 0; mi < 2; ++mi)
            #pragma unroll
            for (int ni = 0; ni < 2; ++ni)
                acc[mi][ni] = __builtin_amdgcn_mfma_f32_16x16x32_f16(af[mi], bf[ni], acc[mi][ni], 0, 0, 0);
        __syncthreads();
    }
    #pragma unroll
    for (int mi = 0; mi < 2; ++mi){
        #pragma unroll
        for (int ni = 0; ni < 2; ++ni){
            int n = n0 + wc*32 + ni*16 + lr;
            float bv = srb[n];
            #pragma unroll
            for (int j = 0; j < 4; ++j){
                int mm = m0 + wr*32 + mi*16 + lg*4 + j;
                Xc[(size_t)mm*256 + n] = acc[mi][ni][j] + bv;
            }
        }
    }
}

// ---------------- LayerNorm over D=256, f32 in -> f16 out ----------------
__launch_bounds__(256)
__global__ void ln_kernel(const float* __restrict__ X, f16* __restrict__ Xo,
                          const float* __restrict__ g, const float* __restrict__ b){
    __shared__ float red[256];
    int row = blockIdx.x, t = threadIdx.x;
    float v = X[(size_t)row*256 + t];
    red[t] = v; __syncthreads();
    #pragma unroll
    for (int s=128; s>0; s>>=1){
        if (t < s) red[t] += red[t+s];
        __syncthreads();
    }
    float mu = red[0] * (1.f/256.f);
    __syncthreads();
    float dv = v - mu;
    red[t] = dv*dv; __syncthreads();
    #pragma unroll
    for (int s=128; s>0; s>>=1){
        if (t < s) red[t] += red[t+s];
        __syncthreads();
    }
    float var = red[0] * (1.f/256.f);
    Xo[(size_t)row*256 + t] = (f16)(dv * rsqrtf(var + 1e-5f) * g[t] + b[t]);
}

// ---------------- V transpose + fp16: VT[b][d][k] = (f16)V[b][k][d] ----------------
__launch_bounds__(256)
__global__ void vtran_kernel(const float* __restrict__ V, f16* __restrict__ VT){
    __shared__ float LT[32][33];
    int b = blockIdx.z, k0 = blockIdx.x*32, d0 = blockIdx.y*32;
    int t = threadIdx.x;
    int k = t >> 3, c0 = (t & 7)*4;
    float4 v = *(const float4*)&V[((size_t)(b*1024 + k0 + k))*256 + d0 + c0];
    LT[k][c0] = v.x; LT[k][c0+1] = v.y; LT[k][c0+2] = v.z; LT[k][c0+3] = v.w;
    __syncthreads();
    int d = t >> 3, kc0 = (t & 7)*4;
    f16x4 h = { (f16)LT[kc0][d], (f16)LT[kc0+1][d], (f16)LT[kc0+2][d], (f16)LT[kc0+3][d] };
    *(f16x4*)&VT[((size_t)(b*256 + d0 + d))*1024 + k0 + kc0] = h;
}

// ---------------- csum[b*256+d] = sum_k VT[b][d][k] ----------------
__launch_bounds__(256)
__global__ void colsum2_kernel(const f16* __restrict__ VT, float* __restrict__ csum){
    __shared__ float red[256];
    int bd = blockIdx.x, t = threadIdx.x;
    f16x4 h = *(const f16x4*)&VT[(size_t)bd*1024 + t*4];
    red[t] = (float)h[0] + (float)h[1] + (float)h[2] + (float)h[3];
    __syncthreads();
    #pragma unroll
    for (int s = 128; s > 0; s >>= 1){
        if (t < s) red[t] += red[t+s];
        __syncthreads();
    }
    if (t == 0) csum[bd] = red[0];
}

// ---------------- fused MFMA attention ----------------
// Mix folded into Q; swapped QK^T; p~=exp(L)-1 centered PV; InstanceNorm stats inline.
__launch_bounds__(512, 4)
__global__ void attn2_kernel(const f16* __restrict__ Qph, const f16* __restrict__ Kh,
                             const f16* __restrict__ VTh, const float* __restrict__ tfw,
                             const float* __restrict__ tfb, const float* __restrict__ csum,
                             float* __restrict__ outu, float* __restrict__ ssq){
    __shared__ f16 QL[32][264];
    __shared__ f16 KL[32][264];
    __shared__ f16 VTL[256][40];

    const int t  = threadIdx.x;
    const int bb = blockIdx.x >> 7;
    const int q0 = (blockIdx.x & 127) * 32;
    const int o  = t >> 6;
    const int l  = t & 63;
    const int g  = l >> 4;
    const int r  = l & 15;

    // stage Q tile (f16), 32x256
    #pragma unroll
    for (int it = 0; it < 2; ++it){
        int e = t + it*512;
        int row = e >> 5, c0 = (e & 31)*8;
        *(f16x8*)&QL[row][c0] = *(const f16x8*)&Qph[((size_t)(bb*4096 + q0 + row))*256 + c0];
    }
    __syncthreads();

    const float tb = tfb[o];
    f16x8 qf[2][8];
    #pragma unroll
    for (int i = 0; i < 8; ++i){
        f16 sc = (f16)(tfw[o*8 + i] * 0.17677669529663687f);
        f16x8 scv = { sc,sc,sc,sc,sc,sc,sc,sc };
        #pragma unroll
        for (int qs = 0; qs < 2; ++qs){
            f16x8 v = *(const f16x8*)&QL[qs*16 + r][i*32 + g*8];
            qf[qs][i] = v * scv;
        }
    }

    f32x4 oacc[2][2] = { { {0,0,0,0},{0,0,0,0} }, { {0,0,0,0},{0,0,0,0} } };
    float s_part[2]  = {0.f, 0.f};
    float q2_part[2] = {0.f, 0.f};

    const f16* Khb = Kh  + (size_t)bb*1024*256;
    const f16* Vtb = VTh + (size_t)bb*256*1024;

    for (int kc = 0; kc < 1024; kc += 32){
        #pragma unroll
        for (int it = 0; it < 2; ++it){
            int e = t + it*512;
            int row = e >> 5, c = (e & 31)*8;
            *(f16x8*)&KL[row][c] = *(const f16x8*)&Khb[(size_t)(kc + row)*256 + c];
            int d = e >> 2, qt = (e & 3)*8;
            *(f16x8*)&VTL[d][qt] = *(const f16x8*)&Vtb[(size_t)d*1024 + kc + qt];
        }
        __syncthreads();
        #pragma unroll
        for (int ks = 0; ks < 2; ++ks){
            f16x8 kf[8];
            #pragma unroll
            for (int i = 0; i < 8; ++i)
                kf[i] = *(const f16x8*)&KL[ks*16 + r][i*32 + g*8];
            f16x4 va[2];
            #pragma unroll
            for (int dh = 0; dh < 2; ++dh)
                va[dh] = *(const f16x4*)&VTL[o*32 + dh*16 + r][ks*16 + g*4];
            #pragma unroll
            for (int qs = 0; qs < 2; ++qs){
                f32x4 acc = {0,0,0,0};
                #pragma unroll
                for (int i = 0; i < 8; ++i)
                    acc = __builtin_amdgcn_mfma_f32_16x16x32_f16(kf[i], qf[qs][i], acc, 0, 0, 0);
                f16x4 pb;
                float ps = 0.f, ps2 = 0.f;
                #pragma unroll
                for (int j = 0; j < 4; ++j){
                    float p = __expf(acc[j] + tb);
                    ps += p; ps2 += p*p;
                    pb[j] = (f16)(p - 1.0f);
                }
                s_part[qs]  += ps;
                q2_part[qs] += ps2;
                #pragma unroll
                for (int dh = 0; dh < 2; ++dh)
                    oacc[qs][dh] = __builtin_amdgcn_mfma_f32_16x16x16f16(va[dh], pb, oacc[qs][dh], 0, 0, 0);
            }
        }
        __syncthreads();
    }

    float s2tot = 0.f;
    #pragma unroll
    for (int qs = 0; qs < 2; ++qs){
        float s = s_part[qs];
        s += __shfl_xor(s, 16);
        s += __shfl_xor(s, 32);
        float inv = 1.0f / s;
        float corrf = (1.0f - s * (1.0f/1024.0f)) * inv;
        float q2 = q2_part[qs];
        q2 += __shfl_xor(q2, 16);
        q2 += __shfl_xor(q2, 32);
        s2tot += q2 * inv * inv;
        int q = q0 + qs*16 + r;
        #pragma unroll
        for (int dh = 0; dh < 2; ++dh){
            int d = o*32 + dh*16 + g*4;
            float4 cs = *(const float4*)&csum[bb*256 + d];
            float4 ov;
            ov.x = oacc[qs][dh][0]*inv + cs.x*corrf;
            ov.y = oacc[qs][dh][1]*inv + cs.y*corrf;
            ov.z = oacc[qs][dh][2]*inv + cs.z*corrf;
            ov.w = oacc[qs][dh][3]*inv + cs.w*corrf;
            *(float4*)&outu[((size_t)(bb*4096 + q))*256 + d] = ov;
        }
    }
    s2tot *= 0.25f;
    #pragma unroll
    for (int off = 1; off < 64; off <<= 1)
        s2tot += __shfl_xor(s2tot, off);
    if (l == 0) atomicAdd(&ssq[bb*8 + o], s2tot);
}

// ---------------- rs[b,h] = rsqrt(ssq/(NQ*NK) - mu^2 + eps) ----------------
__global__ void rs_kernel(const float* __restrict__ ssq, float* __restrict__ rs){
    int t = threadIdx.x;
    const float mu = 1.f/1024.f;
    float var = ssq[t] * (1.f/(4096.f*1024.f)) - mu*mu;
    rs[t] = rsqrtf(var + 1e-5f);
}

// ---------------- final MFMA: C = (rs*outu)(f32->f16) @ WoT^T + bo ----------------
__launch_bounds__(256)
__global__ void final_mfma_kernel(const float* __restrict__ A, const f16* __restrict__ WoT,
                                  const float* __restrict__ rsb, const float* __restrict__ bo,
                                  float* __restrict__ C){
    __shared__ f16 As[128][40];
    __shared__ f16 Bs[128][40];
    int t = threadIdx.x;
    int wid = t >> 6, l = t & 63;
    int wr = wid >> 1, wc = wid & 1;
    int lr = l & 15, lg = l >> 4;
    int m0 = blockIdx.x * 128, n0 = blockIdx.y * 128;
    int bbatch = m0 >> 12;

    f32x4 acc[4][4] = {};
    for (int k0 = 0; k0 < 256; k0 += 32){
        float rsk = rsb[bbatch*8 + (k0 >> 5)];
        #pragma unroll
        for (int i = 0; i < 2; ++i){
            int e = t + i*256, r = e >> 2, c8 = (e & 3)*8;
            const float* ap = &A[(size_t)(m0+r)*256 + k0 + c8];
            float4 v0 = *(const float4*)ap;
            float4 v1 = *(const float4*)(ap+4);
            f16x8 h = { (f16)(v0.x*rsk),(f16)(v0.y*rsk),(f16)(v0.z*rsk),(f16)(v0.w*rsk),
                        (f16)(v1.x*rsk),(f16)(v1.y*rsk),(f16)(v1.z*rsk),(f16)(v1.w*rsk) };
            *(f16x8*)&As[r][c8] = h;
        }
        #pragma unroll
        for (int i = 0; i < 2; ++i){
            int e = t + i*256, r = e >> 2, c8 = (e & 3)*8;
            *(f16x8*)&Bs[r][c8] = *(const f16x8*)&WoT[(size_t)(n0+r)*256 + k0 + c8];
        }
        __syncthreads();
        f16x8 af[4], bf[4];
        #pragma unroll
        for (int mi = 0; mi < 4; ++mi)
            af[mi] = *(const f16x8*)&As[wr*64 + mi*16 + lr][lg*8];
        #pragma unroll
        for (int ni = 0; ni < 4; ++ni)
            bf[ni] = *(const f16x8*)&Bs[wc*64 + ni*16 + lr][lg*8];
        #pragma unroll
        for (int mi = 0; mi < 4; ++mi)
            #pragma unroll
            for (int ni = 0; ni < 4; ++ni)
                acc[mi][ni] = __builtin_amdgcn_mfma_f32_16x16x32_f16(af[mi], bf[ni], acc[mi][ni], 0, 0, 0);
        __syncthreads();
    }
    #pragma unroll
    for (int mi = 0; mi < 4; ++mi){
        #pragma unroll
        for (int ni = 0; ni < 4; ++ni){
            int n = n0 + wc*64 + ni*16 + lr;
            float bv = bo[n];
            #pragma unroll
            for (int j = 0; j < 4; ++j){
                int m = m0 + wr*64 + mi*16 + lg*4 + j;
                C[(size_t)m*256 + n] = acc[mi][ni][j] + bv;
            }
        }
    }
}

extern "C" void kernel_launch(void* const* d_in, const int* in_sizes, int n_in,
                              void* d_out, int out_size, void* d_ws, size_t ws_size,
                              hipStream_t stream) {
    const float* query = (const float*)d_in[0];
    const float* Wq  = (const float*)d_in[3];
    const float* bq  = (const float*)d_in[4];
    const float* Wk  = (const float*)d_in[5];
    const float* bk  = (const float*)d_in[6];
    const float* Wv  = (const float*)d_in[7];
    const float* bv  = (const float*)d_in[8];
    const float* Wo  = (const float*)d_in[9];
    const float* bo  = (const float*)d_in[10];
    const float* srw = (const float*)d_in[11];
    const float* srb = (const float*)d_in[12];
    const float* lng = (const float*)d_in[13];
    const float* lnb = (const float*)d_in[14];
    const float* tfw = (const float*)d_in[15];
    const float* tfb = (const float*)d_in[16];
    float* out = (float*)d_out;

    float* ws = (float*)d_ws;
    float* outu  = ws;                         // 4,194,304 f32
    f16*   qh    = (f16*)(ws + 4194304);       // 16384x256 f16
    f16*   qbh   = (f16*)(ws + 6291456);       // 16384x256 f16
    float* xconv = ws + 8388608;               // 4096x256 f32
    float* vbuf  = ws + 9437184;               // 4096x256 f32
    f16*   xh    = (f16*)(ws + 10485760);      // 4096x256 f16
    f16*   kh    = (f16*)(ws + 11010048);      // 4096x256 f16
    f16*   vth   = (f16*)(ws + 11534336);      // 4x256x1024 f16
    f16*   wtT   = (f16*)(ws + 12058624);      // 256x2304 f16
    f16*   WqT   = (f16*)(ws + 12353536);      // 256x256 f16
    f16*   WkT   = (f16*)(ws + 12386304);
    f16*   WvT   = (f16*)(ws + 12419072);
    f16*   WoT   = (f16*)(ws + 12451840);
    float* csum  = ws + 12484608;              // 1024
    float* ssq   = ws + 12485632;              // 32
    float* rsb   = ws + 12485664;              // 32

    zero32_kernel<<<1, 32, 0, stream>>>(ssq);
    qcvt_kernel<<<2048, 256, 0, stream>>>(query, qh);
    wcvtT_kernel<<<dim3(8,8), 256, 0, stream>>>(Wq, WqT);
    wcvtT_kernel<<<dim3(8,8), 256, 0, stream>>>(Wk, WkT);
    wcvtT_kernel<<<dim3(8,8), 256, 0, stream>>>(Wv, WvT);
    wcvtT_kernel<<<dim3(8,8), 256, 0, stream>>>(Wo, WoT);
    convwT_kernel<<<256, 256, 0, stream>>>(srw, wtT);

    // q projection -> f16
    mfma_gemm<128,128,true><<<dim3(128,2), 256, 0, stream>>>(qh, WqT, bq, qbh, 256);
    // spatial-reduction conv -> f32, then LN -> f16
    conv_mfma_kernel<<<dim3(64,4), 256, 0, stream>>>(qh, wtT, srb, xconv);
    ln_kernel<<<4096, 256, 0, stream>>>(xconv, xh, lng, lnb);
    // k, v projections
    mfma_gemm<64,64,true><<<dim3(64,4), 256, 0, stream>>>(xh, WkT, bk, kh, 256);
    mfma_gemm<64,64,false><<<dim3(64,4), 256, 0, stream>>>(xh, WvT, bv, vbuf, 256);
    vtran_kernel<<<dim3(32, 8, 4), 256, 0, stream>>>(vbuf, vth);
    colsum2_kernel<<<1024, 256, 0, stream>>>(vth, csum);
    // fused MFMA attention
    attn2_kernel<<<512, 512, 0, stream>>>(qbh, kh, vth, tfw, tfb, csum, outu, ssq);
    rs_kernel<<<1, 32, 0, stream>>>(ssq, rsb);
    // output projection with folded instance-norm scale
    final_mfma_kernel<<<dim3(128,2), 256, 0, stream>>>(outu, WoT, rsb, bo, out);
}